// Round 2
// 148.808 us; speedup vs baseline: 1.0462x; 1.0462x over previous
//
#include <hip/hip_runtime.h>

// CTC loss forward (reduction='none', zero_infinity=True), matching the JAX ref.
// Shapes: log_probs (T,N,C)=(512,512,80) fp32, targets (N,S)=(512,128) i32.
// Output: (N,) fp32.
//
// R11: LINEAR-DOMAIN RECURRENCE with WAVE-UNIFORM EXPONENT.
// R10 post-mortem: per-lane exponent E + dead-lane adoption lagged the
// alpha-frontier (frontier advances 1 lane / 2 steps, E adoption 1 lane /
// 8 steps, live E decays ~50 bits/renorm) -> ldexp(sm1, dEm) saturated to
// inf/0 at the frontier -> loss flushed to 0 -> absmax ~= full loss. Fix:
// ONE exponent for the whole wave. Renorm every U_=8 steps re-centers the
// FULL-WAVE max to 2^60 (6 DPP fmax row_shr1/2/4/8 + row_bcast15/31 +
// readlane 63 -> uniform SGPR shift; no LDS, no cross-lane scale mismatch
// ever). fp32 gives >=186 bits of relative range below the wave max (ref's
// own f32 lse drops at 24 bits); worst-case decay between renorms is
// ~14 bits/frame * 8 << 186, and emissions <=1 with 67 bits of headroom
// above 2^60 make overflow impossible. Serial chain per step is now
// dpp -> add -> add -> mul (no transcendentals): the 3 emission exp2's are
// computed one step ahead from the 8-deep load ring, off the chain.
// ctc_comb / ctc_fused unchanged (proven).

#define NEGC  (-1.0e30f)
#define LOG2E 1.4426950408889634f
#define LN2   0.6931471805599453f

constexpr int T_ = 512;
constexpr int C_ = 80;
constexpr int S_ = 128;
constexpr int U_ = 8;        // register-ring depth / unroll / renorm period
constexpr int WROW = 520;    // ws floats per n: ga @0 (257), gg @260 (257)

__device__ __forceinline__ float exp2a(float x) { return __builtin_amdgcn_exp2f(x); }
__device__ __forceinline__ float log2a(float x) { return __builtin_amdgcn_logf(x); }

template <int CTRL>
__device__ __forceinline__ float dppf(float old_, float src) {
    return __int_as_float(__builtin_amdgcn_update_dpp(
        __float_as_int(old_), __float_as_int(src), CTRL, 0xF, 0xF, false));
}

// full-wave max -> bit pattern of max, uniform (SGPR). Lanes reduce via DPP:
// row_shr 1/2/4/8 (within each 16-lane row, invalid lanes keep old = own,
// harmless for max), then row_bcast15 (lane15->row1, lane47->row3) and
// row_bcast31 (lane31->rows2,3): lane 63 holds the full 64-lane max.
__device__ __forceinline__ int wave_max_bits(float m) {
    m = fmaxf(m, dppf<0x111>(m, m));   // row_shr:1
    m = fmaxf(m, dppf<0x112>(m, m));   // row_shr:2
    m = fmaxf(m, dppf<0x114>(m, m));   // row_shr:4
    m = fmaxf(m, dppf<0x118>(m, m));   // row_shr:8
    m = fmaxf(m, dppf<0x142>(m, m));   // row_bcast:15
    m = fmaxf(m, dppf<0x143>(m, m));   // row_bcast:31
    return __builtin_amdgcn_readlane(__float_as_int(m), 63);
}

// classic lse (combine/fallback only)
__device__ __forceinline__ float lse2(float x, float y) {
    float m = fmaxf(x, y);
    return m + log2a(1.0f + exp2a(-fabsf(x - y)));
}
__device__ __forceinline__ float lse3(float x, float y, float z) {
    float m = fmaxf(x, fmaxf(y, z));
    return m + log2a(exp2a(x - m) + exp2a(y - m) + exp2a(z - m));
}

// ---------------- main: one 64-thread block per (n, direction) ----------------
__global__ __launch_bounds__(64) void ctc_half(
    const float* __restrict__ lp, const int* __restrict__ tgt,
    const int* __restrict__ ilen, const int* __restrict__ tlen,
    float* __restrict__ ws, int N)
{
    const int b   = blockIdx.x;
    const int n   = b >> 1;
    const int dir = b & 1;               // 0 = forward, 1 = backward
    const int l   = threadIdx.x;         // lane l owns lattice s=4l..4l+3 (l=63 also 256)

    float* ga = ws + (size_t)n * WROW;        // alpha_{mid-1} (log2)
    float* gg = ga + 260;                     // gamma_mid (log2)

    const int* tn = tgt + n * S_;
    const int ext1 = tn[2 * l];
    const int ext3 = tn[2 * l + 1];
    const int prev = (l > 0) ? tn[2 * l - 1] : 0;
    const bool skip1 = (l > 0) && (ext1 != prev);                     // skip_ok[4l+1]
    const bool skip3 = (ext3 != ext1);                                // skip_ok[4l+3] == bwd skb1
    const bool skb3  = (l < 63) && (tn[2 * l + 2] != ext3);           // skip_ok[4l+5]

    int len = ilen[n];
    len = len < 1 ? 1 : (len > T_ ? T_ : len);
    const int mid = len >> 1;            // fwd frames 0..mid-1; bwd frames mid..len-1

    const size_t rstride = (size_t)N * C_;
    const float* lpn = lp + (size_t)n * C_;
    const float* pB = lpn;
    const float* p1 = lpn + ext1;
    const float* p3 = lpn + ext3;

    float rb[U_], r1[U_], r3[U_];

    if (dir == 0) {
        // ---------------- forward: alpha_{mid-1} ----------------
        const int last = mid - 1 > 0 ? mid - 1 : 0;
        #pragma unroll
        for (int u = 0; u < U_; ++u) {
            const int r = u + 1;
            const int rc = r < mid ? r : last;
            const size_t o = (size_t)rc * rstride;
            rb[r & 7] = pB[o]; r1[r & 7] = p1[o]; r3[r & 7] = p3[o];
        }
        float p0_ = 0.f, p1_ = 0.f, p2_ = 0.f, p3_ = 0.f, p4_ = 0.f;
        int   E = -60;
        if (l == 0) {
            p0_ = exp2a(pB[0] * LOG2E + 60.0f);    // scaled by 2^60, E=-60
            p1_ = exp2a(p1[0] * LOG2E + 60.0f);
        }
        // emission-prob pipeline, one step ahead (t=1 lives in slot 1)
        float PbC = exp2a(rb[1] * LOG2E);
        float P1C = exp2a(r1[1] * LOG2E);
        float P3C = exp2a(r3[1] * LOG2E);
        for (int tb = 1; tb < mid; tb += U_) {
            #pragma unroll
            for (int u = 0; u < U_; ++u) {
                const int t = tb + u;
                const int slot = (1 + u) & 7;          // == t & 7
                const int rr = t + U_;
                const int rc = rr < mid ? rr : last;
                const size_t o = (size_t)rc * rstride;
                const float nrb = pB[o], nr1 = p1[o], nr3 = p3[o];
                const int ns = (2 + u) & 7;            // slot of t+1 (not yet overwritten)
                const float PbN = exp2a(rb[ns] * LOG2E);
                const float P1N = exp2a(r1[ns] * LOG2E);
                const float P3N = exp2a(r3[ns] * LOG2E);
                if (t < mid) {
                    const float sm1 = dppf<0x138>(0.0f, p3_);   // lane l-1's p3; l0 -> 0
                    const float i0 = p0_ + sm1;                 // same scale: E is wave-uniform
                    const float i1 = p1_ + p0_ + (skip1 ? sm1 : 0.f);
                    const float i2 = p2_ + p1_;
                    const float i3 = p3_ + p2_ + (skip3 ? p1_ : 0.f);
                    const float i4 = p4_ + p3_;
                    p0_ = i0 * PbC; p1_ = i1 * P1C; p2_ = i2 * PbC;
                    p3_ = i3 * P3C; p4_ = i4 * PbC;             // s=256 (lane 63)
                }
                PbC = PbN; P1C = P1N; P3C = P3N;
                rb[slot] = nrb; r1[slot] = nr1; r3[slot] = nr3;
            }
            // renorm (exact: powers of two; invariant log2(p)+E preserved)
            const int mi = wave_max_bits(
                fmaxf(fmaxf(fmaxf(p0_, p1_), fmaxf(p2_, p3_)), p4_));
            const int e = (mi > 0) ? (((mi >> 23) & 255) - 187) : 0;  // exp(m)-127-60
            E += e;
            p0_ = ldexpf(p0_, -e); p1_ = ldexpf(p1_, -e); p2_ = ldexpf(p2_, -e);
            p3_ = ldexpf(p3_, -e); p4_ = ldexpf(p4_, -e);
        }
        const float fE = (float)E;
        ga[4 * l + 0] = (p0_ > 0.f) ? fmaxf(log2a(p0_) + fE, NEGC) : NEGC;
        ga[4 * l + 1] = (p1_ > 0.f) ? fmaxf(log2a(p1_) + fE, NEGC) : NEGC;
        ga[4 * l + 2] = (p2_ > 0.f) ? fmaxf(log2a(p2_) + fE, NEGC) : NEGC;
        ga[4 * l + 3] = (p3_ > 0.f) ? fmaxf(log2a(p3_) + fE, NEGC) : NEGC;
        if (l == 63) ga[256] = (p4_ > 0.f) ? fmaxf(log2a(p4_) + fE, NEGC) : NEGC;
    } else {
        // ---------------- backward: gamma_mid ----------------
        const int fe = len - 1;
        #pragma unroll
        for (int u = 0; u < U_; ++u) {
            int rc = fe - 1 - u; if (rc < 0) rc = 0;
            const size_t o = (size_t)rc * rstride;
            rb[u] = pB[o]; r1[u] = p1[o]; r3[u] = p3[o];
        }
        const int tl = tlen[n];
        const int sA = 2 * tl, sB = 2 * tl - 1;
        float g0_, g1_, g2_, g3_, g4_;
        int E = -60;
        {
            const size_t o = (size_t)fe * rstride;
            const float ebi = pB[o] * LOG2E + 60.0f;
            const float e1i = p1[o] * LOG2E + 60.0f;
            const float e3i = p3[o] * LOG2E + 60.0f;
            const int s0 = 4 * l;
            g0_ = (s0     == sA)                 ? exp2a(ebi) : 0.f;
            g1_ = (s0 + 1 == sA || s0 + 1 == sB) ? exp2a(e1i) : 0.f;
            g2_ = (s0 + 2 == sA)                 ? exp2a(ebi) : 0.f;
            g3_ = (s0 + 3 == sA || s0 + 3 == sB) ? exp2a(e3i) : 0.f;
            g4_ = (l == 63 && 256 == sA)         ? exp2a(ebi) : 0.f;
        }
        // emission pipeline: first step t=fe-1 lives in slot 0
        float PbC = exp2a(rb[0] * LOG2E);
        float P1C = exp2a(r1[0] * LOG2E);
        float P3C = exp2a(r3[0] * LOG2E);
        for (int tb = fe - 1; tb >= mid; tb -= U_) {
            #pragma unroll
            for (int u = 0; u < U_; ++u) {
                const int t = tb - u;
                const int slot = u;                    // == (fe-1-t) & 7
                int rc = t - U_; if (rc < 0) rc = 0;
                const size_t o = (size_t)rc * rstride;
                const float nrb = pB[o], nr1 = p1[o], nr3 = p3[o];
                const int ns = (u + 1) & 7;            // slot of t-1
                const float PbN = exp2a(rb[ns] * LOG2E);
                const float P1N = exp2a(r1[ns] * LOG2E);
                const float P3N = exp2a(r3[ns] * LOG2E);
                if (t >= mid) {
                    const float x0 = dppf<0x130>(g4_, g0_);    // l+1's g0; l63 -> own g4
                    const float x1 = dppf<0x130>(0.f, g1_);    // l+1's g1; l63 -> 0
                    const float i0 = g0_ + g1_;
                    const float i1 = g1_ + g2_ + (skip3 ? g3_ : 0.f);  // skb1==skip3
                    const float i2 = g2_ + g3_;
                    const float i3 = g3_ + x0 + (skb3 ? x1 : 0.f);
                    g0_ = i0 * PbC; g1_ = i1 * P1C; g2_ = i2 * PbC;
                    g3_ = i3 * P3C; g4_ = g4_ * PbC;            // s=256: stay only
                }
                PbC = PbN; P1C = P1N; P3C = P3N;
                rb[slot] = nrb; r1[slot] = nr1; r3[slot] = nr3;
            }
            const int mi = wave_max_bits(
                fmaxf(fmaxf(fmaxf(g0_, g1_), fmaxf(g2_, g3_)), g4_));
            const int e = (mi > 0) ? (((mi >> 23) & 255) - 187) : 0;
            E += e;
            g0_ = ldexpf(g0_, -e); g1_ = ldexpf(g1_, -e); g2_ = ldexpf(g2_, -e);
            g3_ = ldexpf(g3_, -e); g4_ = ldexpf(g4_, -e);
        }
        const float fE = (float)E;
        gg[4 * l + 0] = (g0_ > 0.f) ? fmaxf(log2a(g0_) + fE, NEGC) : NEGC;
        gg[4 * l + 1] = (g1_ > 0.f) ? fmaxf(log2a(g1_) + fE, NEGC) : NEGC;
        gg[4 * l + 2] = (g2_ > 0.f) ? fmaxf(log2a(g2_) + fE, NEGC) : NEGC;
        gg[4 * l + 3] = (g3_ > 0.f) ? fmaxf(log2a(g3_) + fE, NEGC) : NEGC;
        if (l == 63) gg[256] = (g4_ > 0.f) ? fmaxf(log2a(g4_) + fE, NEGC) : NEGC;
    }
}

// ---------------- combine: P = sum_s abar[s] * gamma_mid[s] ----------------
__global__ __launch_bounds__(64) void ctc_comb(
    const float* __restrict__ ws, const int* __restrict__ tgt,
    const int* __restrict__ ilen, const int* __restrict__ tlen,
    float* __restrict__ out, int N)
{
    const int n = blockIdx.x;
    const int l = threadIdx.x;
    const float* ga = ws + (size_t)n * WROW;
    const float* gg = ga + 260;

    int len = ilen[n];
    len = len < 1 ? 1 : (len > T_ ? T_ : len);
    const int tl = tlen[n];

    if (len == 1) {                      // degenerate: loss directly from alpha_0
        if (l == 0) {
            const float v1 = ga[2 * tl];
            const float v2 = (2 * tl >= 1) ? ga[2 * tl - 1] : NEGC;
            float loss = -lse2(v1, v2) * LN2;
            if (!(loss < 1e10f) || !isfinite(loss)) loss = 0.0f;
            out[n] = loss;
        }
        return;
    }

    const int* tn = tgt + n * S_;
    const int ext1 = tn[2 * l];
    const int ext3 = tn[2 * l + 1];
    const int prev = (l > 0) ? tn[2 * l - 1] : 0;
    const bool skip1 = (l > 0) && (ext1 != prev);
    const bool skip3 = (ext3 != ext1);

    const int s0 = 4 * l;
    const float Am1 = (l > 0) ? ga[s0 - 1] : NEGC;
    const float A0 = ga[s0], A1 = ga[s0 + 1], A2 = ga[s0 + 2], A3 = ga[s0 + 3];
    const float v0 = lse2(A0, Am1)                    + gg[s0];
    const float v1 = lse3(A1, A0, skip1 ? Am1 : NEGC) + gg[s0 + 1];
    const float v2 = lse2(A2, A1)                     + gg[s0 + 2];
    const float v3 = lse3(A3, A2, skip3 ? A1 : NEGC)  + gg[s0 + 3];
    const float v4 = (l == 63) ? (lse2(ga[256], A3) + gg[256]) : NEGC;

    float m = fmaxf(fmaxf(v0, v1), fmaxf(fmaxf(v2, v3), v4));
    float ssum = exp2a(v0 - m) + exp2a(v1 - m) + exp2a(v2 - m)
               + exp2a(v3 - m) + exp2a(v4 - m);
    float M = m;
    #pragma unroll
    for (int d = 1; d < 64; d <<= 1) M = fmaxf(M, __shfl_xor(M, d));
    float r = ssum * exp2a(m - M);
    #pragma unroll
    for (int d = 1; d < 64; d <<= 1) r += __shfl_xor(r, d);
    if (l == 0) {
        float loss = -LN2 * (M + log2a(r));
        if (!(loss < 1e10f) || !isfinite(loss)) loss = 0.0f;
        out[n] = loss;
    }
}

// ---------------- fallback: exact R8 fused kernel (proven, absmax 0.0) ----------------
__global__ __launch_bounds__(128) void ctc_fused(
    const float* __restrict__ lp, const int* __restrict__ tgt,
    const int* __restrict__ ilen, const int* __restrict__ tlen,
    float* __restrict__ out, int N)
{
    const int n    = blockIdx.x;
    const int wave = threadIdx.x >> 6;
    const int l    = threadIdx.x & 63;

    __shared__ float ga[2 * S_ + 1];
    __shared__ float gg[2 * S_ + 1];

    const int* tn = tgt + n * S_;
    const int ext1 = tn[2 * l];
    const int ext3 = tn[2 * l + 1];
    const int prev = (l > 0) ? tn[2 * l - 1] : 0;
    const bool skip1 = (l > 0) && (ext1 != prev);
    const bool skip3 = (ext3 != ext1);
    const bool skb1 = (tn[2 * l + 1] != tn[2 * l]);
    const bool skb3 = (l < 63) && (tn[2 * l + 2] != tn[2 * l + 1]);

    int len = ilen[n];
    len = len < 1 ? 1 : (len > T_ ? T_ : len);
    const int mid = len >> 1;

    const size_t rstride = (size_t)N * C_;
    const float* lpn = lp + (size_t)n * C_;
    const float* pB = lpn;
    const float* p1 = lpn + ext1;
    const float* p3 = lpn + ext3;

    float rb[U_], r1[U_], r3[U_];

    if (wave == 0) {
        const int last = mid - 1 > 0 ? mid - 1 : 0;
        #pragma unroll
        for (int u = 0; u < U_; ++u) {
            const int r = u + 1;
            const int rc = r < mid ? r : last;
            const size_t o = (size_t)rc * rstride;
            rb[r & 7] = pB[o]; r1[r & 7] = p1[o]; r3[r & 7] = p3[o];
        }
        float a0 = NEGC, a1 = NEGC, a2 = NEGC, a3 = NEGC, a4 = NEGC;
        {
            const float i0 = pB[0] * LOG2E;
            const float i1 = p1[0] * LOG2E;
            if (l == 0) { a0 = i0; a1 = i1; }
        }
        for (int tb = 1; tb < mid; tb += U_) {
            #pragma unroll
            for (int u = 0; u < U_; ++u) {
                const int t = tb + u;
                const int slot = (1 + u) & 7;
                const float eb = rb[slot] * LOG2E;
                const float e1 = r1[slot] * LOG2E;
                const float e3 = r3[slot] * LOG2E;
                const int rr = t + U_;
                const int rc = rr < mid ? rr : last;
                const size_t o = (size_t)rc * rstride;
                const float nrb = pB[o], nr1 = p1[o], nr3 = p3[o];
                if (t < mid) {
                    const float sm1 = dppf<0x138>(NEGC, a3);
                    const float z1 = skip1 ? sm1 : NEGC;
                    const float z3 = skip3 ? a1  : NEGC;
                    const float n0 = lse2(a0, sm1)    + eb;
                    const float n1 = lse3(a1, a0, z1) + e1;
                    const float n2 = lse2(a2, a1)     + eb;
                    const float n3 = lse3(a3, a2, z3) + e3;
                    const float n4 = lse2(a4, a3)     + eb;
                    a0 = n0; a1 = n1; a2 = n2; a3 = n3; a4 = n4;
                }
                rb[slot] = nrb; r1[slot] = nr1; r3[slot] = nr3;
            }
        }
        ga[4 * l + 0] = a0; ga[4 * l + 1] = a1;
        ga[4 * l + 2] = a2; ga[4 * l + 3] = a3;
        if (l == 63) ga[256] = a4;
    } else {
        const int fe = len - 1;
        #pragma unroll
        for (int u = 0; u < U_; ++u) {
            int rc = fe - 1 - u; if (rc < 0) rc = 0;
            const size_t o = (size_t)rc * rstride;
            rb[u] = pB[o]; r1[u] = p1[o]; r3[u] = p3[o];
        }
        const int tl = tlen[n];
        const int sA = 2 * tl, sB = 2 * tl - 1;
        float g0, g1, g2, g3, g4;
        {
            const size_t o = (size_t)fe * rstride;
            const float ebi = pB[o] * LOG2E;
            const float e1i = p1[o] * LOG2E;
            const float e3i = p3[o] * LOG2E;
            const int s0 = 4 * l;
            g0 = (s0     == sA)                 ? ebi : NEGC;
            g1 = (s0 + 1 == sA || s0 + 1 == sB) ? e1i : NEGC;
            g2 = (s0 + 2 == sA)                 ? ebi : NEGC;
            g3 = (s0 + 3 == sA || s0 + 3 == sB) ? e3i : NEGC;
            g4 = (l == 63 && 256 == sA)         ? ebi : NEGC;
        }
        for (int tb = fe - 1; tb >= mid; tb -= U_) {
            #pragma unroll
            for (int u = 0; u < U_; ++u) {
                const int t = tb - u;
                const int slot = ((fe - 1 - tb) + u) & 7;
                const float eb = rb[slot] * LOG2E;
                const float e1 = r1[slot] * LOG2E;
                const float e3 = r3[slot] * LOG2E;
                int rc = t - U_; if (rc < 0) rc = 0;
                const size_t o = (size_t)rc * rstride;
                const float nrb = pB[o], nr1 = p1[o], nr3 = p3[o];
                if (t >= mid) {
                    const float nx0 = dppf<0x130>(g4,   g0);
                    const float nx1 = dppf<0x130>(NEGC, g1);
                    const float z1 = skb1 ? g3  : NEGC;
                    const float z3 = skb3 ? nx1 : NEGC;
                    const float n0 = lse2(g0, g1)      + eb;
                    const float n1 = lse3(g1, g2, z1)  + e1;
                    const float n2 = lse2(g2, g3)      + eb;
                    const float n3 = lse3(g3, nx0, z3) + e3;
                    const float n4 = g4 + eb;
                    g0 = n0; g1 = n1; g2 = n2; g3 = n3; g4 = n4;
                }
                rb[slot] = nrb; r1[slot] = nr1; r3[slot] = nr3;
            }
        }
        gg[4 * l + 0] = g0; gg[4 * l + 1] = g1;
        gg[4 * l + 2] = g2; gg[4 * l + 3] = g3;
        if (l == 63) gg[256] = g4;
    }

    __syncthreads();

    if (wave == 0) {
        const int tl = tlen[n];
        if (len == 1) {
            if (l == 0) {
                const float v1 = ga[2 * tl];
                const float v2 = (2 * tl >= 1) ? ga[2 * tl - 1] : NEGC;
                float loss = -lse2(v1, v2) * LN2;
                if (!(loss < 1e10f) || !isfinite(loss)) loss = 0.0f;
                out[n] = loss;
            }
            return;
        }
        const int s0 = 4 * l;
        const float Am1 = (l > 0) ? ga[s0 - 1] : NEGC;
        const float A0 = ga[s0], A1 = ga[s0 + 1], A2 = ga[s0 + 2], A3 = ga[s0 + 3];
        const float v0 = lse2(A0, Am1)                    + gg[s0];
        const float v1 = lse3(A1, A0, skip1 ? Am1 : NEGC) + gg[s0 + 1];
        const float v2 = lse2(A2, A1)                     + gg[s0 + 2];
        const float v3 = lse3(A3, A2, skip3 ? A1 : NEGC)  + gg[s0 + 3];
        const float v4 = (l == 63) ? (lse2(ga[256], A3) + gg[256]) : NEGC;

        float m = fmaxf(fmaxf(v0, v1), fmaxf(fmaxf(v2, v3), v4));
        float ssum = exp2a(v0 - m) + exp2a(v1 - m) + exp2a(v2 - m)
                   + exp2a(v3 - m) + exp2a(v4 - m);
        float M = m;
        #pragma unroll
        for (int d = 1; d < 64; d <<= 1) M = fmaxf(M, __shfl_xor(M, d));
        float r = ssum * exp2a(m - M);
        #pragma unroll
        for (int d = 1; d < 64; d <<= 1) r += __shfl_xor(r, d);
        if (l == 0) {
            float loss = -LN2 * (M + log2a(r));
            if (!(loss < 1e10f) || !isfinite(loss)) loss = 0.0f;
            out[n] = loss;
        }
    }
}

extern "C" void kernel_launch(void* const* d_in, const int* in_sizes, int n_in,
                              void* d_out, int out_size, void* d_ws, size_t ws_size,
                              hipStream_t stream) {
    const float* lp  = (const float*)d_in[0];
    const int*   tg  = (const int*)  d_in[1];
    const int*   il  = (const int*)  d_in[2];
    const int*   tl  = (const int*)  d_in[3];
    float*       out = (float*)d_out;
    const int N = in_sizes[2];  // 512
    const size_t need = (size_t)N * WROW * sizeof(float);  // ~1.06 MB
    if (ws_size >= need) {
        ctc_half<<<2 * N, 64, 0, stream>>>(lp, tg, il, tl, (float*)d_ws, N);
        ctc_comb<<<N, 64, 0, stream>>>((const float*)d_ws, tg, il, tl, out, N);
    } else {
        ctc_fused<<<N, 128, 0, stream>>>(lp, tg, il, tl, out, N);  // proven R8 path
    }
}

// Round 3
// 147.887 us; speedup vs baseline: 1.0528x; 1.0062x over previous
//
#include <hip/hip_runtime.h>

// CTC loss forward (reduction='none', zero_infinity=True), matching the JAX ref.
// Shapes: log_probs (T,N,C)=(512,512,80) fp32, targets (N,S)=(512,128) i32.
// Output: (N,) fp32.
//
// R12: REGISTER-BUDGET FIX. R11 post-mortem: linear-domain rewrite removed
// 8/11 trans ops but ctc_half only went ~58 -> ~52us (~490 cyc/step vs ~90
// issue estimate). VGPR_Count=36 proves the 24-float prefetch ring
// rb/r1/r3[8] (+5 state +3 emission regs + pointers ~= 50 live) was NOT in
// registers: the allocator targeted 8-waves/SIMD occupancy (useless here --
// grid puts ~1 wave/SIMD) and spilled the ring / sank the prefetch loads,
// putting a scratch/L2 round-trip (~400cy) on the serial chain every step.
// This also retro-explains R8's "2-wave contention" (scratch/L1 thrash, not
// the trans pipe) and VALUBusy=30% (vmcnt-stalled, not issuing).
// Fix: __launch_bounds__(64, 1) (min 1 wave/EU -> full VGPR budget) so the
// ring lives in registers and the 8-step prefetch covers memory latency.
// Everything else identical to the PASSED R11 (absmax 0.0).
//
// R11: LINEAR-DOMAIN RECURRENCE with WAVE-UNIFORM EXPONENT.
// One exponent E for the whole wave; renorm every U_=8 steps re-centers the
// full-wave max to 2^60 (6 DPP fmax + readlane -> uniform shift; exact
// powers of two). fp32 gives >=186 bits of relative range below the wave
// max (ref's own f32 lse drops at 24 bits); emissions <=1 with 67 bits of
// headroom above 2^60 make overflow impossible. Serial chain per step:
// dpp -> add -> add -> mul (no transcendentals); the 3 emission exp2's are
// computed one step ahead from the 8-deep load ring, off the chain.
// ctc_comb / ctc_fused unchanged (proven).

#define NEGC  (-1.0e30f)
#define LOG2E 1.4426950408889634f
#define LN2   0.6931471805599453f

constexpr int T_ = 512;
constexpr int C_ = 80;
constexpr int S_ = 128;
constexpr int U_ = 8;        // register-ring depth / unroll / renorm period
constexpr int WROW = 520;    // ws floats per n: ga @0 (257), gg @260 (257)

__device__ __forceinline__ float exp2a(float x) { return __builtin_amdgcn_exp2f(x); }
__device__ __forceinline__ float log2a(float x) { return __builtin_amdgcn_logf(x); }

template <int CTRL>
__device__ __forceinline__ float dppf(float old_, float src) {
    return __int_as_float(__builtin_amdgcn_update_dpp(
        __float_as_int(old_), __float_as_int(src), CTRL, 0xF, 0xF, false));
}

// full-wave max -> bit pattern of max, uniform (SGPR). Lanes reduce via DPP:
// row_shr 1/2/4/8 (within each 16-lane row, invalid lanes keep old = own,
// harmless for max), then row_bcast15 (lane15->row1, lane47->row3) and
// row_bcast31 (lane31->rows2,3): lane 63 holds the full 64-lane max.
__device__ __forceinline__ int wave_max_bits(float m) {
    m = fmaxf(m, dppf<0x111>(m, m));   // row_shr:1
    m = fmaxf(m, dppf<0x112>(m, m));   // row_shr:2
    m = fmaxf(m, dppf<0x114>(m, m));   // row_shr:4
    m = fmaxf(m, dppf<0x118>(m, m));   // row_shr:8
    m = fmaxf(m, dppf<0x142>(m, m));   // row_bcast:15
    m = fmaxf(m, dppf<0x143>(m, m));   // row_bcast:31
    return __builtin_amdgcn_readlane(__float_as_int(m), 63);
}

// classic lse (combine/fallback only)
__device__ __forceinline__ float lse2(float x, float y) {
    float m = fmaxf(x, y);
    return m + log2a(1.0f + exp2a(-fabsf(x - y)));
}
__device__ __forceinline__ float lse3(float x, float y, float z) {
    float m = fmaxf(x, fmaxf(y, z));
    return m + log2a(exp2a(x - m) + exp2a(y - m) + exp2a(z - m));
}

// ---------------- main: one 64-thread block per (n, direction) ----------------
__global__ __launch_bounds__(64, 1) void ctc_half(
    const float* __restrict__ lp, const int* __restrict__ tgt,
    const int* __restrict__ ilen, const int* __restrict__ tlen,
    float* __restrict__ ws, int N)
{
    const int b   = blockIdx.x;
    const int n   = b >> 1;
    const int dir = b & 1;               // 0 = forward, 1 = backward
    const int l   = threadIdx.x;         // lane l owns lattice s=4l..4l+3 (l=63 also 256)

    float* ga = ws + (size_t)n * WROW;        // alpha_{mid-1} (log2)
    float* gg = ga + 260;                     // gamma_mid (log2)

    const int* tn = tgt + n * S_;
    const int ext1 = tn[2 * l];
    const int ext3 = tn[2 * l + 1];
    const int prev = (l > 0) ? tn[2 * l - 1] : 0;
    const bool skip1 = (l > 0) && (ext1 != prev);                     // skip_ok[4l+1]
    const bool skip3 = (ext3 != ext1);                                // skip_ok[4l+3] == bwd skb1
    const bool skb3  = (l < 63) && (tn[2 * l + 2] != ext3);           // skip_ok[4l+5]

    int len = ilen[n];
    len = len < 1 ? 1 : (len > T_ ? T_ : len);
    const int mid = len >> 1;            // fwd frames 0..mid-1; bwd frames mid..len-1

    const size_t rstride = (size_t)N * C_;
    const float* lpn = lp + (size_t)n * C_;
    const float* pB = lpn;
    const float* p1 = lpn + ext1;
    const float* p3 = lpn + ext3;

    float rb[U_], r1[U_], r3[U_];

    if (dir == 0) {
        // ---------------- forward: alpha_{mid-1} ----------------
        const int last = mid - 1 > 0 ? mid - 1 : 0;
        #pragma unroll
        for (int u = 0; u < U_; ++u) {
            const int r = u + 1;
            const int rc = r < mid ? r : last;
            const size_t o = (size_t)rc * rstride;
            rb[r & 7] = pB[o]; r1[r & 7] = p1[o]; r3[r & 7] = p3[o];
        }
        float p0_ = 0.f, p1_ = 0.f, p2_ = 0.f, p3_ = 0.f, p4_ = 0.f;
        int   E = -60;
        if (l == 0) {
            p0_ = exp2a(pB[0] * LOG2E + 60.0f);    // scaled by 2^60, E=-60
            p1_ = exp2a(p1[0] * LOG2E + 60.0f);
        }
        // emission-prob pipeline, one step ahead (t=1 lives in slot 1)
        float PbC = exp2a(rb[1] * LOG2E);
        float P1C = exp2a(r1[1] * LOG2E);
        float P3C = exp2a(r3[1] * LOG2E);
        for (int tb = 1; tb < mid; tb += U_) {
            #pragma unroll
            for (int u = 0; u < U_; ++u) {
                const int t = tb + u;
                const int slot = (1 + u) & 7;          // == t & 7
                const int rr = t + U_;
                const int rc = rr < mid ? rr : last;
                const size_t o = (size_t)rc * rstride;
                const float nrb = pB[o], nr1 = p1[o], nr3 = p3[o];
                const int ns = (2 + u) & 7;            // slot of t+1 (not yet overwritten)
                const float PbN = exp2a(rb[ns] * LOG2E);
                const float P1N = exp2a(r1[ns] * LOG2E);
                const float P3N = exp2a(r3[ns] * LOG2E);
                if (t < mid) {
                    const float sm1 = dppf<0x138>(0.0f, p3_);   // lane l-1's p3; l0 -> 0
                    const float i0 = p0_ + sm1;                 // same scale: E is wave-uniform
                    const float i1 = p1_ + p0_ + (skip1 ? sm1 : 0.f);
                    const float i2 = p2_ + p1_;
                    const float i3 = p3_ + p2_ + (skip3 ? p1_ : 0.f);
                    const float i4 = p4_ + p3_;
                    p0_ = i0 * PbC; p1_ = i1 * P1C; p2_ = i2 * PbC;
                    p3_ = i3 * P3C; p4_ = i4 * PbC;             // s=256 (lane 63)
                }
                PbC = PbN; P1C = P1N; P3C = P3N;
                rb[slot] = nrb; r1[slot] = nr1; r3[slot] = nr3;
            }
            // renorm (exact: powers of two; invariant log2(p)+E preserved)
            const int mi = wave_max_bits(
                fmaxf(fmaxf(fmaxf(p0_, p1_), fmaxf(p2_, p3_)), p4_));
            const int e = (mi > 0) ? (((mi >> 23) & 255) - 187) : 0;  // exp(m)-127-60
            E += e;
            p0_ = ldexpf(p0_, -e); p1_ = ldexpf(p1_, -e); p2_ = ldexpf(p2_, -e);
            p3_ = ldexpf(p3_, -e); p4_ = ldexpf(p4_, -e);
        }
        const float fE = (float)E;
        ga[4 * l + 0] = (p0_ > 0.f) ? fmaxf(log2a(p0_) + fE, NEGC) : NEGC;
        ga[4 * l + 1] = (p1_ > 0.f) ? fmaxf(log2a(p1_) + fE, NEGC) : NEGC;
        ga[4 * l + 2] = (p2_ > 0.f) ? fmaxf(log2a(p2_) + fE, NEGC) : NEGC;
        ga[4 * l + 3] = (p3_ > 0.f) ? fmaxf(log2a(p3_) + fE, NEGC) : NEGC;
        if (l == 63) ga[256] = (p4_ > 0.f) ? fmaxf(log2a(p4_) + fE, NEGC) : NEGC;
    } else {
        // ---------------- backward: gamma_mid ----------------
        const int fe = len - 1;
        #pragma unroll
        for (int u = 0; u < U_; ++u) {
            int rc = fe - 1 - u; if (rc < 0) rc = 0;
            const size_t o = (size_t)rc * rstride;
            rb[u] = pB[o]; r1[u] = p1[o]; r3[u] = p3[o];
        }
        const int tl = tlen[n];
        const int sA = 2 * tl, sB = 2 * tl - 1;
        float g0_, g1_, g2_, g3_, g4_;
        int E = -60;
        {
            const size_t o = (size_t)fe * rstride;
            const float ebi = pB[o] * LOG2E + 60.0f;
            const float e1i = p1[o] * LOG2E + 60.0f;
            const float e3i = p3[o] * LOG2E + 60.0f;
            const int s0 = 4 * l;
            g0_ = (s0     == sA)                 ? exp2a(ebi) : 0.f;
            g1_ = (s0 + 1 == sA || s0 + 1 == sB) ? exp2a(e1i) : 0.f;
            g2_ = (s0 + 2 == sA)                 ? exp2a(ebi) : 0.f;
            g3_ = (s0 + 3 == sA || s0 + 3 == sB) ? exp2a(e3i) : 0.f;
            g4_ = (l == 63 && 256 == sA)         ? exp2a(ebi) : 0.f;
        }
        // emission pipeline: first step t=fe-1 lives in slot 0
        float PbC = exp2a(rb[0] * LOG2E);
        float P1C = exp2a(r1[0] * LOG2E);
        float P3C = exp2a(r3[0] * LOG2E);
        for (int tb = fe - 1; tb >= mid; tb -= U_) {
            #pragma unroll
            for (int u = 0; u < U_; ++u) {
                const int t = tb - u;
                const int slot = u;                    // == (fe-1-t) & 7
                int rc = t - U_; if (rc < 0) rc = 0;
                const size_t o = (size_t)rc * rstride;
                const float nrb = pB[o], nr1 = p1[o], nr3 = p3[o];
                const int ns = (u + 1) & 7;            // slot of t-1
                const float PbN = exp2a(rb[ns] * LOG2E);
                const float P1N = exp2a(r1[ns] * LOG2E);
                const float P3N = exp2a(r3[ns] * LOG2E);
                if (t >= mid) {
                    const float x0 = dppf<0x130>(g4_, g0_);    // l+1's g0; l63 -> own g4
                    const float x1 = dppf<0x130>(0.f, g1_);    // l+1's g1; l63 -> 0
                    const float i0 = g0_ + g1_;
                    const float i1 = g1_ + g2_ + (skip3 ? g3_ : 0.f);  // skb1==skip3
                    const float i2 = g2_ + g3_;
                    const float i3 = g3_ + x0 + (skb3 ? x1 : 0.f);
                    g0_ = i0 * PbC; g1_ = i1 * P1C; g2_ = i2 * PbC;
                    g3_ = i3 * P3C; g4_ = g4_ * PbC;            // s=256: stay only
                }
                PbC = PbN; P1C = P1N; P3C = P3N;
                rb[slot] = nrb; r1[slot] = nr1; r3[slot] = nr3;
            }
            const int mi = wave_max_bits(
                fmaxf(fmaxf(fmaxf(g0_, g1_), fmaxf(g2_, g3_)), g4_));
            const int e = (mi > 0) ? (((mi >> 23) & 255) - 187) : 0;
            E += e;
            g0_ = ldexpf(g0_, -e); g1_ = ldexpf(g1_, -e); g2_ = ldexpf(g2_, -e);
            g3_ = ldexpf(g3_, -e); g4_ = ldexpf(g4_, -e);
        }
        const float fE = (float)E;
        gg[4 * l + 0] = (g0_ > 0.f) ? fmaxf(log2a(g0_) + fE, NEGC) : NEGC;
        gg[4 * l + 1] = (g1_ > 0.f) ? fmaxf(log2a(g1_) + fE, NEGC) : NEGC;
        gg[4 * l + 2] = (g2_ > 0.f) ? fmaxf(log2a(g2_) + fE, NEGC) : NEGC;
        gg[4 * l + 3] = (g3_ > 0.f) ? fmaxf(log2a(g3_) + fE, NEGC) : NEGC;
        if (l == 63) gg[256] = (g4_ > 0.f) ? fmaxf(log2a(g4_) + fE, NEGC) : NEGC;
    }
}

// ---------------- combine: P = sum_s abar[s] * gamma_mid[s] ----------------
__global__ __launch_bounds__(64) void ctc_comb(
    const float* __restrict__ ws, const int* __restrict__ tgt,
    const int* __restrict__ ilen, const int* __restrict__ tlen,
    float* __restrict__ out, int N)
{
    const int n = blockIdx.x;
    const int l = threadIdx.x;
    const float* ga = ws + (size_t)n * WROW;
    const float* gg = ga + 260;

    int len = ilen[n];
    len = len < 1 ? 1 : (len > T_ ? T_ : len);
    const int tl = tlen[n];

    if (len == 1) {                      // degenerate: loss directly from alpha_0
        if (l == 0) {
            const float v1 = ga[2 * tl];
            const float v2 = (2 * tl >= 1) ? ga[2 * tl - 1] : NEGC;
            float loss = -lse2(v1, v2) * LN2;
            if (!(loss < 1e10f) || !isfinite(loss)) loss = 0.0f;
            out[n] = loss;
        }
        return;
    }

    const int* tn = tgt + n * S_;
    const int ext1 = tn[2 * l];
    const int ext3 = tn[2 * l + 1];
    const int prev = (l > 0) ? tn[2 * l - 1] : 0;
    const bool skip1 = (l > 0) && (ext1 != prev);
    const bool skip3 = (ext3 != ext1);

    const int s0 = 4 * l;
    const float Am1 = (l > 0) ? ga[s0 - 1] : NEGC;
    const float A0 = ga[s0], A1 = ga[s0 + 1], A2 = ga[s0 + 2], A3 = ga[s0 + 3];
    const float v0 = lse2(A0, Am1)                    + gg[s0];
    const float v1 = lse3(A1, A0, skip1 ? Am1 : NEGC) + gg[s0 + 1];
    const float v2 = lse2(A2, A1)                     + gg[s0 + 2];
    const float v3 = lse3(A3, A2, skip3 ? A1 : NEGC)  + gg[s0 + 3];
    const float v4 = (l == 63) ? (lse2(ga[256], A3) + gg[256]) : NEGC;

    float m = fmaxf(fmaxf(v0, v1), fmaxf(fmaxf(v2, v3), v4));
    float ssum = exp2a(v0 - m) + exp2a(v1 - m) + exp2a(v2 - m)
               + exp2a(v3 - m) + exp2a(v4 - m);
    float M = m;
    #pragma unroll
    for (int d = 1; d < 64; d <<= 1) M = fmaxf(M, __shfl_xor(M, d));
    float r = ssum * exp2a(m - M);
    #pragma unroll
    for (int d = 1; d < 64; d <<= 1) r += __shfl_xor(r, d);
    if (l == 0) {
        float loss = -LN2 * (M + log2a(r));
        if (!(loss < 1e10f) || !isfinite(loss)) loss = 0.0f;
        out[n] = loss;
    }
}

// ---------------- fallback: exact R8 fused kernel (proven, absmax 0.0) ----------------
__global__ __launch_bounds__(128) void ctc_fused(
    const float* __restrict__ lp, const int* __restrict__ tgt,
    const int* __restrict__ ilen, const int* __restrict__ tlen,
    float* __restrict__ out, int N)
{
    const int n    = blockIdx.x;
    const int wave = threadIdx.x >> 6;
    const int l    = threadIdx.x & 63;

    __shared__ float ga[2 * S_ + 1];
    __shared__ float gg[2 * S_ + 1];

    const int* tn = tgt + n * S_;
    const int ext1 = tn[2 * l];
    const int ext3 = tn[2 * l + 1];
    const int prev = (l > 0) ? tn[2 * l - 1] : 0;
    const bool skip1 = (l > 0) && (ext1 != prev);
    const bool skip3 = (ext3 != ext1);
    const bool skb1 = (tn[2 * l + 1] != tn[2 * l]);
    const bool skb3 = (l < 63) && (tn[2 * l + 2] != tn[2 * l + 1]);

    int len = ilen[n];
    len = len < 1 ? 1 : (len > T_ ? T_ : len);
    const int mid = len >> 1;

    const size_t rstride = (size_t)N * C_;
    const float* lpn = lp + (size_t)n * C_;
    const float* pB = lpn;
    const float* p1 = lpn + ext1;
    const float* p3 = lpn + ext3;

    float rb[U_], r1[U_], r3[U_];

    if (wave == 0) {
        const int last = mid - 1 > 0 ? mid - 1 : 0;
        #pragma unroll
        for (int u = 0; u < U_; ++u) {
            const int r = u + 1;
            const int rc = r < mid ? r : last;
            const size_t o = (size_t)rc * rstride;
            rb[r & 7] = pB[o]; r1[r & 7] = p1[o]; r3[r & 7] = p3[o];
        }
        float a0 = NEGC, a1 = NEGC, a2 = NEGC, a3 = NEGC, a4 = NEGC;
        {
            const float i0 = pB[0] * LOG2E;
            const float i1 = p1[0] * LOG2E;
            if (l == 0) { a0 = i0; a1 = i1; }
        }
        for (int tb = 1; tb < mid; tb += U_) {
            #pragma unroll
            for (int u = 0; u < U_; ++u) {
                const int t = tb + u;
                const int slot = (1 + u) & 7;
                const float eb = rb[slot] * LOG2E;
                const float e1 = r1[slot] * LOG2E;
                const float e3 = r3[slot] * LOG2E;
                const int rr = t + U_;
                const int rc = rr < mid ? rr : last;
                const size_t o = (size_t)rc * rstride;
                const float nrb = pB[o], nr1 = p1[o], nr3 = p3[o];
                if (t < mid) {
                    const float sm1 = dppf<0x138>(NEGC, a3);
                    const float z1 = skip1 ? sm1 : NEGC;
                    const float z3 = skip3 ? a1  : NEGC;
                    const float n0 = lse2(a0, sm1)    + eb;
                    const float n1 = lse3(a1, a0, z1) + e1;
                    const float n2 = lse2(a2, a1)     + eb;
                    const float n3 = lse3(a3, a2, z3) + e3;
                    const float n4 = lse2(a4, a3)     + eb;
                    a0 = n0; a1 = n1; a2 = n2; a3 = n3; a4 = n4;
                }
                rb[slot] = nrb; r1[slot] = nr1; r3[slot] = nr3;
            }
        }
        ga[4 * l + 0] = a0; ga[4 * l + 1] = a1;
        ga[4 * l + 2] = a2; ga[4 * l + 3] = a3;
        if (l == 63) ga[256] = a4;
    } else {
        const int fe = len - 1;
        #pragma unroll
        for (int u = 0; u < U_; ++u) {
            int rc = fe - 1 - u; if (rc < 0) rc = 0;
            const size_t o = (size_t)rc * rstride;
            rb[u] = pB[o]; r1[u] = p1[o]; r3[u] = p3[o];
        }
        const int tl = tlen[n];
        const int sA = 2 * tl, sB = 2 * tl - 1;
        float g0, g1, g2, g3, g4;
        {
            const size_t o = (size_t)fe * rstride;
            const float ebi = pB[o] * LOG2E;
            const float e1i = p1[o] * LOG2E;
            const float e3i = p3[o] * LOG2E;
            const int s0 = 4 * l;
            g0 = (s0     == sA)                 ? ebi : NEGC;
            g1 = (s0 + 1 == sA || s0 + 1 == sB) ? e1i : NEGC;
            g2 = (s0 + 2 == sA)                 ? ebi : NEGC;
            g3 = (s0 + 3 == sA || s0 + 3 == sB) ? e3i : NEGC;
            g4 = (l == 63 && 256 == sA)         ? ebi : NEGC;
        }
        for (int tb = fe - 1; tb >= mid; tb -= U_) {
            #pragma unroll
            for (int u = 0; u < U_; ++u) {
                const int t = tb - u;
                const int slot = ((fe - 1 - tb) + u) & 7;
                const float eb = rb[slot] * LOG2E;
                const float e1 = r1[slot] * LOG2E;
                const float e3 = r3[slot] * LOG2E;
                int rc = t - U_; if (rc < 0) rc = 0;
                const size_t o = (size_t)rc * rstride;
                const float nrb = pB[o], nr1 = p1[o], nr3 = p3[o];
                if (t >= mid) {
                    const float nx0 = dppf<0x130>(g4,   g0);
                    const float nx1 = dppf<0x130>(NEGC, g1);
                    const float z1 = skb1 ? g3  : NEGC;
                    const float z3 = skb3 ? nx1 : NEGC;
                    const float n0 = lse2(g0, g1)      + eb;
                    const float n1 = lse3(g1, g2, z1)  + e1;
                    const float n2 = lse2(g2, g3)      + eb;
                    const float n3 = lse3(g3, nx0, z3) + e3;
                    const float n4 = g4 + eb;
                    g0 = n0; g1 = n1; g2 = n2; g3 = n3; g4 = n4;
                }
                rb[slot] = nrb; r1[slot] = nr1; r3[slot] = nr3;
            }
        }
        gg[4 * l + 0] = g0; gg[4 * l + 1] = g1;
        gg[4 * l + 2] = g2; gg[4 * l + 3] = g3;
        if (l == 63) gg[256] = g4;
    }

    __syncthreads();

    if (wave == 0) {
        const int tl = tlen[n];
        if (len == 1) {
            if (l == 0) {
                const float v1 = ga[2 * tl];
                const float v2 = (2 * tl >= 1) ? ga[2 * tl - 1] : NEGC;
                float loss = -lse2(v1, v2) * LN2;
                if (!(loss < 1e10f) || !isfinite(loss)) loss = 0.0f;
                out[n] = loss;
            }
            return;
        }
        const int s0 = 4 * l;
        const float Am1 = (l > 0) ? ga[s0 - 1] : NEGC;
        const float A0 = ga[s0], A1 = ga[s0 + 1], A2 = ga[s0 + 2], A3 = ga[s0 + 3];
        const float v0 = lse2(A0, Am1)                    + gg[s0];
        const float v1 = lse3(A1, A0, skip1 ? Am1 : NEGC) + gg[s0 + 1];
        const float v2 = lse2(A2, A1)                     + gg[s0 + 2];
        const float v3 = lse3(A3, A2, skip3 ? A1 : NEGC)  + gg[s0 + 3];
        const float v4 = (l == 63) ? (lse2(ga[256], A3) + gg[256]) : NEGC;

        float m = fmaxf(fmaxf(v0, v1), fmaxf(fmaxf(v2, v3), v4));
        float ssum = exp2a(v0 - m) + exp2a(v1 - m) + exp2a(v2 - m)
                   + exp2a(v3 - m) + exp2a(v4 - m);
        float M = m;
        #pragma unroll
        for (int d = 1; d < 64; d <<= 1) M = fmaxf(M, __shfl_xor(M, d));
        float r = ssum * exp2a(m - M);
        #pragma unroll
        for (int d = 1; d < 64; d <<= 1) r += __shfl_xor(r, d);
        if (l == 0) {
            float loss = -LN2 * (M + log2a(r));
            if (!(loss < 1e10f) || !isfinite(loss)) loss = 0.0f;
            out[n] = loss;
        }
    }
}

extern "C" void kernel_launch(void* const* d_in, const int* in_sizes, int n_in,
                              void* d_out, int out_size, void* d_ws, size_t ws_size,
                              hipStream_t stream) {
    const float* lp  = (const float*)d_in[0];
    const int*   tg  = (const int*)  d_in[1];
    const int*   il  = (const int*)  d_in[2];
    const int*   tl  = (const int*)  d_in[3];
    float*       out = (float*)d_out;
    const int N = in_sizes[2];  // 512
    const size_t need = (size_t)N * WROW * sizeof(float);  // ~1.06 MB
    if (ws_size >= need) {
        ctc_half<<<2 * N, 64, 0, stream>>>(lp, tg, il, tl, (float*)d_ws, N);
        ctc_comb<<<N, 64, 0, stream>>>((const float*)d_ws, tg, il, tl, out, N);
    } else {
        ctc_fused<<<N, 128, 0, stream>>>(lp, tg, il, tl, out, N);  // proven R8 path
    }
}

// Round 4
// 131.858 us; speedup vs baseline: 1.1807x; 1.1216x over previous
//
#include <hip/hip_runtime.h>

// CTC loss forward (reduction='none', zero_infinity=True), matching the JAX ref.
// Shapes: log_probs (T,N,C)=(512,512,80) fp32, targets (N,S)=(512,128) i32.
// Output: (N,) fp32.
//
// R13: LDS-STAGED EMISSION PIPELINE. R12 post-mortem: raising the VGPR
// budget (launch_bounds(64,1)) was NULL (-0.9us), and R11's trans removal
// saved only its issue cycles (-6.9us ~= 8 trans x 8cyc x 256 steps). So
// ~490 cyc/step of stall is NOT trans and NOT a pure register-budget
// problem: it matches ONE exposed first-touch-HBM round-trip per step
// (~900cy latency, every (n,t) row is read exactly once by one block).
// The 8-deep per-lane register ring never actually kept 24 loads in
// flight (R0: VGPR_Count=36 cannot; R12: budget raise changed nothing).
// Fix: make latency-hiding STRUCTURAL. Stage whole 80-float rows into LDS
// in batches of 8 frames (10 coalesced wave-loads per batch, 2.5KB/half,
// double-buffered), issued TWO epochs (16 steps ~= 1000cy) before use, with
// one dependency-counted vmcnt wait per batch (overlapped by a full epoch
// of compute). Per step the emissions are 3 ds_reads (blank=broadcast,
// ext1/ext3 = gathers) prefetched 2 steps ahead + 3 exp2 off the serial
// chain. In-flight register state: 2 x 10 staging regs + ~25 others.
// Recurrence/renorm/seeds bit-compatible with the PASSED R11 (absmax 0.0).
//
// R11: LINEAR-DOMAIN RECURRENCE with WAVE-UNIFORM EXPONENT. One exponent E
// per wave; renorm every 8 steps re-centers the full-wave max to 2^60
// (6 DPP fmax + readlane; exact powers of two). Serial chain per step:
// dpp -> add -> add -> mul. ctc_comb / ctc_fused unchanged (proven).

#define NEGC  (-1.0e30f)
#define LOG2E 1.4426950408889634f
#define LN2   0.6931471805599453f

constexpr int T_ = 512;
constexpr int C_ = 80;
constexpr int S_ = 128;
constexpr int U_ = 8;        // epoch length / renorm period
constexpr int WROW = 520;    // ws floats per n: ga @0 (257), gg @260 (257)

__device__ __forceinline__ float exp2a(float x) { return __builtin_amdgcn_exp2f(x); }
__device__ __forceinline__ float log2a(float x) { return __builtin_amdgcn_logf(x); }

template <int CTRL>
__device__ __forceinline__ float dppf(float old_, float src) {
    return __int_as_float(__builtin_amdgcn_update_dpp(
        __float_as_int(old_), __float_as_int(src), CTRL, 0xF, 0xF, false));
}

// full-wave max -> bit pattern of max, uniform (SGPR).
__device__ __forceinline__ int wave_max_bits(float m) {
    m = fmaxf(m, dppf<0x111>(m, m));   // row_shr:1
    m = fmaxf(m, dppf<0x112>(m, m));   // row_shr:2
    m = fmaxf(m, dppf<0x114>(m, m));   // row_shr:4
    m = fmaxf(m, dppf<0x118>(m, m));   // row_shr:8
    m = fmaxf(m, dppf<0x142>(m, m));   // row_bcast:15
    m = fmaxf(m, dppf<0x143>(m, m));   // row_bcast:31
    return __builtin_amdgcn_readlane(__float_as_int(m), 63);
}

// classic lse (combine/fallback only)
__device__ __forceinline__ float lse2(float x, float y) {
    float m = fmaxf(x, y);
    return m + log2a(1.0f + exp2a(-fabsf(x - y)));
}
__device__ __forceinline__ float lse3(float x, float y, float z) {
    float m = fmaxf(x, fmaxf(y, z));
    return m + log2a(exp2a(x - m) + exp2a(y - m) + exp2a(z - m));
}

// ---------------- main: one 64-thread block per (n, direction) ----------------
__global__ __launch_bounds__(64, 1) void ctc_half(
    const float* __restrict__ lp, const int* __restrict__ tgt,
    const int* __restrict__ ilen, const int* __restrict__ tlen,
    float* __restrict__ ws, int N)
{
    const int b   = blockIdx.x;
    const int n   = b >> 1;
    const int dir = b & 1;               // 0 = forward, 1 = backward
    const int l   = threadIdx.x;         // lane l owns lattice s=4l..4l+3 (l=63 also 256)

    // LDS: 2 halves x 8 frames x 80 floats (log2-domain: raw*LOG2E folded at write)
    __shared__ float lds[1280];

    float* ga = ws + (size_t)n * WROW;        // alpha_{mid-1} (log2)
    float* gg = ga + 260;                     // gamma_mid (log2)

    const int* tn = tgt + n * S_;
    const int ext1 = tn[2 * l];
    const int ext3 = tn[2 * l + 1];
    const int prev = (l > 0) ? tn[2 * l - 1] : 0;
    const bool skip1 = (l > 0) && (ext1 != prev);                     // skip_ok[4l+1]
    const bool skip3 = (ext3 != ext1);                                // skip_ok[4l+3] == bwd skb1
    const bool skb3  = (l < 63) && (tn[2 * l + 2] != ext3);           // skip_ok[4l+5]

    int len = ilen[n];
    len = len < 1 ? 1 : (len > T_ ? T_ : len);
    const int mid = len >> 1;            // fwd frames 0..mid-1; bwd frames mid..len-1

    const int irst = N * C_;             // 40960: frame stride in floats (fits i32 math)
    const float* lpn = lp + (size_t)n * C_;

    // per-lane staging constants: flat = l + 64k -> row dk, col ck within a batch.
    // LDS word offset for flat is just flat itself (row-major [8][80]).
    int dkr[10], ckk[10];
    #pragma unroll
    for (int k = 0; k < 10; ++k) {
        const unsigned flat = (unsigned)l + 64u * k;
        const unsigned dk = flat / 80u;
        ckk[k] = (int)(flat - 80u * dk);
        dkr[k] = (int)dk * irst;
    }

    float VA[10], VB[10];

#define SISSUE_F(FB, V) do {                                                   \
    const int s_ = (FB) * irst;                                                \
    _Pragma("unroll")                                                          \
    for (int k = 0; k < 10; ++k)                                               \
        V[k] = lpn[(unsigned)(s_ + dkr[k] + ckk[k])];                          \
} while (0)

#define SISSUE_B(FB, V) do {                                                   \
    const int s_ = (FB) * irst;                                                \
    _Pragma("unroll")                                                          \
    for (int k = 0; k < 10; ++k) {                                             \
        int v_ = s_ - dkr[k]; v_ = v_ < 0 ? 0 : v_;                            \
        V[k] = lpn[(unsigned)(v_ + ckk[k])];                                   \
    }                                                                          \
} while (0)

#define SWRITE(H, V) do {                                                      \
    _Pragma("unroll")                                                          \
    for (int k = 0; k < 10; ++k)                                               \
        lds[(H) * 640 + l + 64 * k] = V[k] * LOG2E;                            \
} while (0)

#define RENORM(S0, S1, S2, S3, S4) do {                                        \
    const int mi_ = wave_max_bits(                                             \
        fmaxf(fmaxf(fmaxf(S0, S1), fmaxf(S2, S3)), S4));                       \
    const int e_ = (mi_ > 0) ? (((mi_ >> 23) & 255) - 187) : 0;                \
    E += e_;                                                                   \
    S0 = ldexpf(S0, -e_); S1 = ldexpf(S1, -e_); S2 = ldexpf(S2, -e_);          \
    S3 = ldexpf(S3, -e_); S4 = ldexpf(S4, -e_);                                \
} while (0)

    if (dir == 0) {
        // ---------------- forward: alpha_{mid-1} ----------------
        // frame f (f>=1) lives at LDS row idx f-1: half ((idx>>3)&1), row idx&7.
        SISSUE_F(1, VA);  SWRITE(0, VA);      // batch 0: frames 1..8
        SISSUE_F(9, VB);  SWRITE(1, VB);      // batch 1: frames 9..16
        SISSUE_F(17, VA);                      // batch 2 in flight

        float p0_ = 0.f, p1_ = 0.f, p2_ = 0.f, p3_ = 0.f, p4_ = 0.f;
        int   E = -60;
        if (l == 0) {
            p0_ = exp2a(lpn[0] * LOG2E + 60.0f);     // scaled by 2^60, E=-60
            p1_ = exp2a(lpn[ext1] * LOG2E + 60.0f);
        }
        // emission pipeline: PbC/P1C/P3C = frame 1 (exp'd); rbN.. = frame 2 (raw log2)
        float PbC = exp2a(lds[0]);
        float P1C = exp2a(lds[ext1]);
        float P3C = exp2a(lds[ext3]);
        float rbN = lds[80], r1N = lds[80 + ext1], r3N = lds[80 + ext3];

#define FWD_STEP(T_EXPR) do {                                                  \
    const int t_ = (T_EXPR);                                                   \
    const int idx2_ = t_ + 1;              /* LDS row of frame t+2 */          \
    const int ofs2_ = ((idx2_ >> 3) & 1) * 640 + (idx2_ & 7) * 80;             \
    const float rb2_ = lds[ofs2_];                                             \
    const float r12_ = lds[ofs2_ + ext1];                                      \
    const float r32_ = lds[ofs2_ + ext3];                                      \
    const float PbN_ = exp2a(rbN), P1N_ = exp2a(r1N), P3N_ = exp2a(r3N);       \
    if (t_ < mid) {                                                            \
        const float sm1_ = dppf<0x138>(0.0f, p3_);  /* lane l-1's p3 */        \
        const float i0_ = p0_ + sm1_;                                          \
        const float i1_ = p1_ + p0_ + (skip1 ? sm1_ : 0.f);                    \
        const float i2_ = p2_ + p1_;                                           \
        const float i3_ = p3_ + p2_ + (skip3 ? p1_ : 0.f);                     \
        const float i4_ = p4_ + p3_;                                           \
        p0_ = i0_ * PbC; p1_ = i1_ * P1C; p2_ = i2_ * PbC;                     \
        p3_ = i3_ * P3C; p4_ = i4_ * PbC;                                      \
    }                                                                          \
    PbC = PbN_; P1C = P1N_; P3C = P3N_;                                        \
    rbN = rb2_; r1N = r12_; r3N = r32_;                                        \
} while (0)

        for (int tb = 1; tb < mid; tb += 16) {
            // epoch A: frames tb..tb+7 from half 0 (batch j, j even)
            #pragma unroll
            for (int u = 0; u < 8; ++u) FWD_STEP(tb + u);
            RENORM(p0_, p1_, p2_, p3_, p4_);
            SWRITE(0, VA);                 // batch j+2 -> half 0 (loads issued 2 epochs ago)
            SISSUE_F(tb + 24, VB);         // batch j+3
            // epoch B: frames tb+8..tb+15 from half 1 (batch j+1)
            #pragma unroll
            for (int u = 8; u < 16; ++u) FWD_STEP(tb + u);
            RENORM(p0_, p1_, p2_, p3_, p4_);
            SWRITE(1, VB);                 // batch j+3 -> half 1
            SISSUE_F(tb + 32, VA);         // batch j+4 (frames <= 294 < 512: safe)
        }
        const float fE = (float)E;
        ga[4 * l + 0] = (p0_ > 0.f) ? fmaxf(log2a(p0_) + fE, NEGC) : NEGC;
        ga[4 * l + 1] = (p1_ > 0.f) ? fmaxf(log2a(p1_) + fE, NEGC) : NEGC;
        ga[4 * l + 2] = (p2_ > 0.f) ? fmaxf(log2a(p2_) + fE, NEGC) : NEGC;
        ga[4 * l + 3] = (p3_ > 0.f) ? fmaxf(log2a(p3_) + fE, NEGC) : NEGC;
        if (l == 63) ga[256] = (p4_ > 0.f) ? fmaxf(log2a(p4_) + fE, NEGC) : NEGC;
    } else {
        // ---------------- backward: gamma_mid ----------------
        const int fe = len - 1;
        // frame f lives at LDS row idx fe-1-f.
        SISSUE_B(fe - 1, VA);  SWRITE(0, VA);    // batch 0: frames fe-1..fe-8 (clamped >=0)
        SISSUE_B(fe - 9, VB);  SWRITE(1, VB);    // batch 1
        SISSUE_B(fe - 17, VA);                    // batch 2 in flight

        const int tl = tlen[n];
        const int sA = 2 * tl, sB = 2 * tl - 1;
        float g0_, g1_, g2_, g3_, g4_;
        int E = -60;
        {
            const unsigned feo = (unsigned)(fe * irst);
            const float ebi = lpn[feo] * LOG2E + 60.0f;
            const float e1i = lpn[feo + ext1] * LOG2E + 60.0f;
            const float e3i = lpn[feo + ext3] * LOG2E + 60.0f;
            const int s0 = 4 * l;
            g0_ = (s0     == sA)                 ? exp2a(ebi) : 0.f;
            g1_ = (s0 + 1 == sA || s0 + 1 == sB) ? exp2a(e1i) : 0.f;
            g2_ = (s0 + 2 == sA)                 ? exp2a(ebi) : 0.f;
            g3_ = (s0 + 3 == sA || s0 + 3 == sB) ? exp2a(e3i) : 0.f;
            g4_ = (l == 63 && 256 == sA)         ? exp2a(ebi) : 0.f;
        }
        // emission pipeline: PbC = frame fe-1 (exp'd); rbN.. = frame fe-2 (raw log2)
        float PbC = exp2a(lds[0]);
        float P1C = exp2a(lds[ext1]);
        float P3C = exp2a(lds[ext3]);
        float rbN = lds[80], r1N = lds[80 + ext1], r3N = lds[80 + ext3];

#define BWD_STEP(T_EXPR) do {                                                  \
    const int t_ = (T_EXPR);                                                   \
    const int idx2_ = fe + 1 - t_;         /* LDS row of frame t-2 */          \
    const int ofs2_ = ((idx2_ >> 3) & 1) * 640 + (idx2_ & 7) * 80;             \
    const float rb2_ = lds[ofs2_];                                             \
    const float r12_ = lds[ofs2_ + ext1];                                      \
    const float r32_ = lds[ofs2_ + ext3];                                      \
    const float PbN_ = exp2a(rbN), P1N_ = exp2a(r1N), P3N_ = exp2a(r3N);       \
    if (t_ >= mid) {                                                           \
        const float x0_ = dppf<0x130>(g4_, g0_);  /* l+1's g0; l63 -> g4 */    \
        const float x1_ = dppf<0x130>(0.f, g1_);  /* l+1's g1; l63 -> 0  */    \
        const float i0_ = g0_ + g1_;                                           \
        const float i1_ = g1_ + g2_ + (skip3 ? g3_ : 0.f);                     \
        const float i2_ = g2_ + g3_;                                           \
        const float i3_ = g3_ + x0_ + (skb3 ? x1_ : 0.f);                      \
        g0_ = i0_ * PbC; g1_ = i1_ * P1C; g2_ = i2_ * PbC;                     \
        g3_ = i3_ * P3C; g4_ = g4_ * PbC;                                      \
    }                                                                          \
    PbC = PbN_; P1C = P1N_; P3C = P3N_;                                        \
    rbN = rb2_; r1N = r12_; r3N = r32_;                                        \
} while (0)

        for (int tb = fe - 1; tb >= mid; tb -= 16) {
            // epoch A: frames tb..tb-7 from half 0
            #pragma unroll
            for (int u = 0; u < 8; ++u) BWD_STEP(tb - u);
            RENORM(g0_, g1_, g2_, g3_, g4_);
            SWRITE(0, VA);
            SISSUE_B(tb - 24, VB);
            // epoch B: frames tb-8..tb-15 from half 1
            #pragma unroll
            for (int u = 8; u < 16; ++u) BWD_STEP(tb - u);
            RENORM(g0_, g1_, g2_, g3_, g4_);
            SWRITE(1, VB);
            SISSUE_B(tb - 32, VA);
        }
        const float fE = (float)E;
        gg[4 * l + 0] = (g0_ > 0.f) ? fmaxf(log2a(g0_) + fE, NEGC) : NEGC;
        gg[4 * l + 1] = (g1_ > 0.f) ? fmaxf(log2a(g1_) + fE, NEGC) : NEGC;
        gg[4 * l + 2] = (g2_ > 0.f) ? fmaxf(log2a(g2_) + fE, NEGC) : NEGC;
        gg[4 * l + 3] = (g3_ > 0.f) ? fmaxf(log2a(g3_) + fE, NEGC) : NEGC;
        if (l == 63) gg[256] = (g4_ > 0.f) ? fmaxf(log2a(g4_) + fE, NEGC) : NEGC;
    }
#undef FWD_STEP
#undef BWD_STEP
#undef SISSUE_F
#undef SISSUE_B
#undef SWRITE
#undef RENORM
}

// ---------------- combine: P = sum_s abar[s] * gamma_mid[s] ----------------
__global__ __launch_bounds__(64) void ctc_comb(
    const float* __restrict__ ws, const int* __restrict__ tgt,
    const int* __restrict__ ilen, const int* __restrict__ tlen,
    float* __restrict__ out, int N)
{
    const int n = blockIdx.x;
    const int l = threadIdx.x;
    const float* ga = ws + (size_t)n * WROW;
    const float* gg = ga + 260;

    int len = ilen[n];
    len = len < 1 ? 1 : (len > T_ ? T_ : len);
    const int tl = tlen[n];

    if (len == 1) {                      // degenerate: loss directly from alpha_0
        if (l == 0) {
            const float v1 = ga[2 * tl];
            const float v2 = (2 * tl >= 1) ? ga[2 * tl - 1] : NEGC;
            float loss = -lse2(v1, v2) * LN2;
            if (!(loss < 1e10f) || !isfinite(loss)) loss = 0.0f;
            out[n] = loss;
        }
        return;
    }

    const int* tn = tgt + n * S_;
    const int ext1 = tn[2 * l];
    const int ext3 = tn[2 * l + 1];
    const int prev = (l > 0) ? tn[2 * l - 1] : 0;
    const bool skip1 = (l > 0) && (ext1 != prev);
    const bool skip3 = (ext3 != ext1);

    const int s0 = 4 * l;
    const float Am1 = (l > 0) ? ga[s0 - 1] : NEGC;
    const float A0 = ga[s0], A1 = ga[s0 + 1], A2 = ga[s0 + 2], A3 = ga[s0 + 3];
    const float v0 = lse2(A0, Am1)                    + gg[s0];
    const float v1 = lse3(A1, A0, skip1 ? Am1 : NEGC) + gg[s0 + 1];
    const float v2 = lse2(A2, A1)                     + gg[s0 + 2];
    const float v3 = lse3(A3, A2, skip3 ? A1 : NEGC)  + gg[s0 + 3];
    const float v4 = (l == 63) ? (lse2(ga[256], A3) + gg[256]) : NEGC;

    float m = fmaxf(fmaxf(v0, v1), fmaxf(fmaxf(v2, v3), v4));
    float ssum = exp2a(v0 - m) + exp2a(v1 - m) + exp2a(v2 - m)
               + exp2a(v3 - m) + exp2a(v4 - m);
    float M = m;
    #pragma unroll
    for (int d = 1; d < 64; d <<= 1) M = fmaxf(M, __shfl_xor(M, d));
    float r = ssum * exp2a(m - M);
    #pragma unroll
    for (int d = 1; d < 64; d <<= 1) r += __shfl_xor(r, d);
    if (l == 0) {
        float loss = -LN2 * (M + log2a(r));
        if (!(loss < 1e10f) || !isfinite(loss)) loss = 0.0f;
        out[n] = loss;
    }
}

// ---------------- fallback: exact R8 fused kernel (proven, absmax 0.0) ----------------
__global__ __launch_bounds__(128) void ctc_fused(
    const float* __restrict__ lp, const int* __restrict__ tgt,
    const int* __restrict__ ilen, const int* __restrict__ tlen,
    float* __restrict__ out, int N)
{
    const int n    = blockIdx.x;
    const int wave = threadIdx.x >> 6;
    const int l    = threadIdx.x & 63;

    __shared__ float ga[2 * S_ + 1];
    __shared__ float gg[2 * S_ + 1];

    const int* tn = tgt + n * S_;
    const int ext1 = tn[2 * l];
    const int ext3 = tn[2 * l + 1];
    const int prev = (l > 0) ? tn[2 * l - 1] : 0;
    const bool skip1 = (l > 0) && (ext1 != prev);
    const bool skip3 = (ext3 != ext1);
    const bool skb1 = (tn[2 * l + 1] != tn[2 * l]);
    const bool skb3 = (l < 63) && (tn[2 * l + 2] != tn[2 * l + 1]);

    int len = ilen[n];
    len = len < 1 ? 1 : (len > T_ ? T_ : len);
    const int mid = len >> 1;

    const size_t rstride = (size_t)N * C_;
    const float* lpn = lp + (size_t)n * C_;
    const float* pB = lpn;
    const float* p1 = lpn + ext1;
    const float* p3 = lpn + ext3;

    float rb[U_], r1[U_], r3[U_];

    if (wave == 0) {
        const int last = mid - 1 > 0 ? mid - 1 : 0;
        #pragma unroll
        for (int u = 0; u < U_; ++u) {
            const int r = u + 1;
            const int rc = r < mid ? r : last;
            const size_t o = (size_t)rc * rstride;
            rb[r & 7] = pB[o]; r1[r & 7] = p1[o]; r3[r & 7] = p3[o];
        }
        float a0 = NEGC, a1 = NEGC, a2 = NEGC, a3 = NEGC, a4 = NEGC;
        {
            const float i0 = pB[0] * LOG2E;
            const float i1 = p1[0] * LOG2E;
            if (l == 0) { a0 = i0; a1 = i1; }
        }
        for (int tb = 1; tb < mid; tb += U_) {
            #pragma unroll
            for (int u = 0; u < U_; ++u) {
                const int t = tb + u;
                const int slot = (1 + u) & 7;
                const float eb = rb[slot] * LOG2E;
                const float e1 = r1[slot] * LOG2E;
                const float e3 = r3[slot] * LOG2E;
                const int rr = t + U_;
                const int rc = rr < mid ? rr : last;
                const size_t o = (size_t)rc * rstride;
                const float nrb = pB[o], nr1 = p1[o], nr3 = p3[o];
                if (t < mid) {
                    const float sm1 = dppf<0x138>(NEGC, a3);
                    const float z1 = skip1 ? sm1 : NEGC;
                    const float z3 = skip3 ? a1  : NEGC;
                    const float n0 = lse2(a0, sm1)    + eb;
                    const float n1 = lse3(a1, a0, z1) + e1;
                    const float n2 = lse2(a2, a1)     + eb;
                    const float n3 = lse3(a3, a2, z3) + e3;
                    const float n4 = lse2(a4, a3)     + eb;
                    a0 = n0; a1 = n1; a2 = n2; a3 = n3; a4 = n4;
                }
                rb[slot] = nrb; r1[slot] = nr1; r3[slot] = nr3;
            }
        }
        ga[4 * l + 0] = a0; ga[4 * l + 1] = a1;
        ga[4 * l + 2] = a2; ga[4 * l + 3] = a3;
        if (l == 63) ga[256] = a4;
    } else {
        const int fe = len - 1;
        #pragma unroll
        for (int u = 0; u < U_; ++u) {
            int rc = fe - 1 - u; if (rc < 0) rc = 0;
            const size_t o = (size_t)rc * rstride;
            rb[u] = pB[o]; r1[u] = p1[o]; r3[u] = p3[o];
        }
        const int tl = tlen[n];
        const int sA = 2 * tl, sB = 2 * tl - 1;
        float g0, g1, g2, g3, g4;
        {
            const size_t o = (size_t)fe * rstride;
            const float ebi = pB[o] * LOG2E;
            const float e1i = p1[o] * LOG2E;
            const float e3i = p3[o] * LOG2E;
            const int s0 = 4 * l;
            g0 = (s0     == sA)                 ? ebi : NEGC;
            g1 = (s0 + 1 == sA || s0 + 1 == sB) ? e1i : NEGC;
            g2 = (s0 + 2 == sA)                 ? ebi : NEGC;
            g3 = (s0 + 3 == sA || s0 + 3 == sB) ? e3i : NEGC;
            g4 = (l == 63 && 256 == sA)         ? ebi : NEGC;
        }
        for (int tb = fe - 1; tb >= mid; tb -= U_) {
            #pragma unroll
            for (int u = 0; u < U_; ++u) {
                const int t = tb - u;
                const int slot = ((fe - 1 - tb) + u) & 7;
                const float eb = rb[slot] * LOG2E;
                const float e1 = r1[slot] * LOG2E;
                const float e3 = r3[slot] * LOG2E;
                int rc = t - U_; if (rc < 0) rc = 0;
                const size_t o = (size_t)rc * rstride;
                const float nrb = pB[o], nr1 = p1[o], nr3 = p3[o];
                if (t >= mid) {
                    const float nx0 = dppf<0x130>(g4,   g0);
                    const float nx1 = dppf<0x130>(NEGC, g1);
                    const float z1 = skb1 ? g3  : NEGC;
                    const float z3 = skb3 ? nx1 : NEGC;
                    const float n0 = lse2(g0, g1)      + eb;
                    const float n1 = lse3(g1, g2, z1)  + e1;
                    const float n2 = lse2(g2, g3)      + eb;
                    const float n3 = lse3(g3, nx0, z3) + e3;
                    const float n4 = g4 + eb;
                    g0 = n0; g1 = n1; g2 = n2; g3 = n3; g4 = n4;
                }
                rb[slot] = nrb; r1[slot] = nr1; r3[slot] = nr3;
            }
        }
        gg[4 * l + 0] = g0; gg[4 * l + 1] = g1;
        gg[4 * l + 2] = g2; gg[4 * l + 3] = g3;
        if (l == 63) gg[256] = g4;
    }

    __syncthreads();

    if (wave == 0) {
        const int tl = tlen[n];
        if (len == 1) {
            if (l == 0) {
                const float v1 = ga[2 * tl];
                const float v2 = (2 * tl >= 1) ? ga[2 * tl - 1] : NEGC;
                float loss = -lse2(v1, v2) * LN2;
                if (!(loss < 1e10f) || !isfinite(loss)) loss = 0.0f;
                out[n] = loss;
            }
            return;
        }
        const int s0 = 4 * l;
        const float Am1 = (l > 0) ? ga[s0 - 1] : NEGC;
        const float A0 = ga[s0], A1 = ga[s0 + 1], A2 = ga[s0 + 2], A3 = ga[s0 + 3];
        const float v0 = lse2(A0, Am1)                    + gg[s0];
        const float v1 = lse3(A1, A0, skip1 ? Am1 : NEGC) + gg[s0 + 1];
        const float v2 = lse2(A2, A1)                     + gg[s0 + 2];
        const float v3 = lse3(A3, A2, skip3 ? A1 : NEGC)  + gg[s0 + 3];
        const float v4 = (l == 63) ? (lse2(ga[256], A3) + gg[256]) : NEGC;

        float m = fmaxf(fmaxf(v0, v1), fmaxf(fmaxf(v2, v3), v4));
        float ssum = exp2a(v0 - m) + exp2a(v1 - m) + exp2a(v2 - m)
                   + exp2a(v3 - m) + exp2a(v4 - m);
        float M = m;
        #pragma unroll
        for (int d = 1; d < 64; d <<= 1) M = fmaxf(M, __shfl_xor(M, d));
        float r = ssum * exp2a(m - M);
        #pragma unroll
        for (int d = 1; d < 64; d <<= 1) r += __shfl_xor(r, d);
        if (l == 0) {
            float loss = -LN2 * (M + log2a(r));
            if (!(loss < 1e10f) || !isfinite(loss)) loss = 0.0f;
            out[n] = loss;
        }
    }
}

extern "C" void kernel_launch(void* const* d_in, const int* in_sizes, int n_in,
                              void* d_out, int out_size, void* d_ws, size_t ws_size,
                              hipStream_t stream) {
    const float* lp  = (const float*)d_in[0];
    const int*   tg  = (const int*)  d_in[1];
    const int*   il  = (const int*)  d_in[2];
    const int*   tl  = (const int*)  d_in[3];
    float*       out = (float*)d_out;
    const int N = in_sizes[2];  // 512
    const size_t need = (size_t)N * WROW * sizeof(float);  // ~1.06 MB
    if (ws_size >= need) {
        ctc_half<<<2 * N, 64, 0, stream>>>(lp, tg, il, tl, (float*)d_ws, N);
        ctc_comb<<<N, 64, 0, stream>>>((const float*)d_ws, tg, il, tl, out, N);
    } else {
        ctc_fused<<<N, 128, 0, stream>>>(lp, tg, il, tl, out, N);  // proven R8 path
    }
}